// Round 4
// baseline (256.167 us; speedup 1.0000x reference)
//
#include <hip/hip_runtime.h>

#define SPLINE_OFF 25165824   // splines output offset (6120 floats follow)
#define STEP_F (1.0f/9.0f)
#define NBLK 256

// ---------------------------------------------------------------------------
// Fused resize: jax.image.resize bilinear antialias, 1024 -> 256 (scale .25).
// Block 0 also zeros the ws stats accumulators AND grid-barrier counters
// (runs before trunk_k in stream order, so every graph replay starts clean).
// ---------------------------------------------------------------------------
__global__ __launch_bounds__(256) void resize_k(const float* __restrict__ x,
                                                float* __restrict__ sm,
                                                float* __restrict__ wsz) {
    __shared__ float vsum[1024];
    const int blk = blockIdx.x;          // 24*256
    const int plane = blk >> 8;
    const int orow = blk & 255;
    const int t = threadIdx.x;
    if (blk == 0) {
        for (int i = t; i < 2560; i += 256) wsz[i] = 0.f;
    }

    const float W[8] = {0.125f,0.375f,0.625f,0.875f,0.875f,0.625f,0.375f,0.125f};
    const float* p = x + (size_t)plane * 1048576 + t * 4;
    const int r0 = 4 * orow - 2;
    float ax = 0.f, ay = 0.f, az = 0.f, aw = 0.f;
    if (r0 >= 0 && r0 + 7 <= 1023) {
        #pragma unroll
        for (int k = 0; k < 8; k++) {
            const float4 v = *(const float4*)(p + (r0 + k) * 1024);
            const float w = W[k] * 0.25f;
            ax = fmaf(v.x, w, ax); ay = fmaf(v.y, w, ay);
            az = fmaf(v.z, w, az); aw = fmaf(v.w, w, aw);
        }
    } else {
        float wsum = 0.f;
        #pragma unroll
        for (int k = 0; k < 8; k++) {
            const int r = r0 + k;
            if (r >= 0 && r < 1024) {
                const float4 v = *(const float4*)(p + r * 1024);
                ax = fmaf(v.x, W[k], ax); ay = fmaf(v.y, W[k], ay);
                az = fmaf(v.z, W[k], az); aw = fmaf(v.w, W[k], aw);
                wsum += W[k];
            }
        }
        const float inv = 1.f / wsum;
        ax *= inv; ay *= inv; az *= inv; aw *= inv;
    }
    vsum[4 * t + 0] = ax; vsum[4 * t + 1] = ay;
    vsum[4 * t + 2] = az; vsum[4 * t + 3] = aw;
    __syncthreads();

    const int c0 = 4 * t - 2;
    float acc = 0.f;
    if (c0 >= 0 && c0 + 7 <= 1023) {
        #pragma unroll
        for (int k = 0; k < 8; k++)
            acc = fmaf(vsum[c0 + k], W[k] * 0.25f, acc);
    } else {
        float wsum = 0.f;
        #pragma unroll
        for (int k = 0; k < 8; k++) {
            const int c = c0 + k;
            if (c >= 0 && c < 1024) { acc = fmaf(vsum[c], W[k], acc); wsum += W[k]; }
        }
        acc /= wsum;
    }
    sm[(size_t)blk * 256 + t] = acc;
}

// ---------------------------------------------------------------------------
// Device-scope grid barrier (persistent kernel, all NBLK blocks co-resident).
// ---------------------------------------------------------------------------
__device__ __forceinline__ void gridbar(unsigned* cnt) {
    __syncthreads();
    if (threadIdx.x == 0) {
        __threadfence();   // release: publish this block's global writes
        __hip_atomic_fetch_add(cnt, 1u, __ATOMIC_ACQ_REL, __HIP_MEMORY_SCOPE_AGENT);
        while (__hip_atomic_load(cnt, __ATOMIC_ACQUIRE, __HIP_MEMORY_SCOPE_AGENT) < (unsigned)NBLK)
            __builtin_amdgcn_s_sleep(1);
        __threadfence();   // acquire: invalidate stale cache before reads
    }
    __syncthreads();
}

// ---------------------------------------------------------------------------
// One conv layer as a phase of the persistent trunk kernel.
// NCO=2 output channels per thread. Work item = (b, co-pair, pixel-tile),
// strided across NBLK blocks. INBN folds the previous layer's BN into the
// activation load; STATS accumulates per-channel sum/sumsq via atomics.
// ---------------------------------------------------------------------------
template<int CIN, int COUT, int INW, int OUTW, int TILES, int NITER,
         bool INBN, bool STATS, bool WRITE>
__device__ __forceinline__ void conv_phase(
    const float* __restrict__ in, const float* __restrict__ w,
    const float* __restrict__ bias, const float* __restrict__ g,
    const float* __restrict__ be, const float* __restrict__ stIn, float invN,
    float* __restrict__ out, float* __restrict__ stOut,
    float* scs, float* shs, float (*red)[2][4], int blk, int t)
{
    constexpr int COG = COUT / 2;
    constexpr int NPIX = OUTW * OUTW;
    if constexpr (INBN) {
        if (t < CIN) {
            float m = stIn[t] * invN;
            float v = stIn[CIN + t] * invN - m * m;
            float sc = g[t] * rsqrtf(v + 1e-5f);
            scs[t] = sc;
            shs[t] = be[t] - m * sc;
        }
        __syncthreads();
    }
    for (int it = 0; it < NITER; ++it) {
        const int item = it * NBLK + blk;
        const int tile = item % TILES;
        const int rest = item / TILES;
        const int co0  = (rest % COG) * 2;
        const int b    = rest / COG;
        const int px   = tile * 256 + t;
        const bool valid = px < NPIX;
        float v0 = 0.f, v1 = 0.f;
        if (valid) {
            const int oh = px / OUTW, ow = px - oh * OUTW;
            const float* ib = in + (size_t)(b * CIN) * (INW * INW)
                                 + (size_t)(2 * oh) * INW + 2 * ow;
            const float* wp = w + (size_t)co0 * CIN * 9;
            float a0 = 0.f, a1 = 0.f;
            for (int ci = 0; ci < CIN; ci++) {
                const float* ip = ib + (size_t)ci * (INW * INW);
                float sc = 1.f, sh = 0.f;
                if constexpr (INBN) { sc = scs[ci]; sh = shs[ci]; }
                #pragma unroll
                for (int kh = 0; kh < 3; kh++) {
                    #pragma unroll
                    for (int kw = 0; kw < 3; kw++) {
                        float xv = ip[kh * INW + kw];
                        if constexpr (INBN) xv = fmaf(xv, sc, sh);
                        a0 = fmaf(xv, wp[ci * 9 + kh * 3 + kw], a0);
                        a1 = fmaf(xv, wp[(CIN + ci) * 9 + kh * 3 + kw], a1);
                    }
                }
            }
            v0 = fmaxf(a0 + bias[co0], 0.f);
            v1 = fmaxf(a1 + bias[co0 + 1], 0.f);
            if constexpr (WRITE) {
                out[(size_t)(b * COUT + co0) * NPIX + px] = v0;
                out[(size_t)(b * COUT + co0 + 1) * NPIX + px] = v1;
            }
        }
        if constexpr (STATS) {
            float s0 = v0, q0 = v0 * v0, s1 = v1, q1 = v1 * v1;
            #pragma unroll
            for (int off = 32; off > 0; off >>= 1) {
                s0 += __shfl_down(s0, off); q0 += __shfl_down(q0, off);
                s1 += __shfl_down(s1, off); q1 += __shfl_down(q1, off);
            }
            const int wid = t >> 6;
            if ((t & 63) == 0) {
                red[0][0][wid] = s0; red[0][1][wid] = q0;
                red[1][0][wid] = s1; red[1][1][wid] = q1;
            }
            __syncthreads();
            if (t == 0) {
                float ts0 = 0.f, tq0 = 0.f, ts1 = 0.f, tq1 = 0.f;
                #pragma unroll
                for (int i = 0; i < 4; i++) {
                    ts0 += red[0][0][i]; tq0 += red[0][1][i];
                    ts1 += red[1][0][i]; tq1 += red[1][1][i];
                }
                atomicAdd(&stOut[co0], ts0);
                atomicAdd(&stOut[COUT + co0], tq0);
                atomicAdd(&stOut[co0 + 1], ts1);
                atomicAdd(&stOut[COUT + co0 + 1], tq1);
            }
            __syncthreads();
        }
    }
}

// ---------------------------------------------------------------------------
// Persistent trunk kernel: conv1..conv5 (+BN folds, stats) with grid barriers,
// then block 0 runs the fc1/fc2 + spline-coefficient tail.
// Grid MUST be NBLK blocks of 256 (all co-resident: 1 block/CU on 256 CUs).
// ---------------------------------------------------------------------------
__global__ __launch_bounds__(256) void trunk_k(
    const float* __restrict__ sm,
    const float* __restrict__ w1, const float* __restrict__ b1,
    const float* __restrict__ w2, const float* __restrict__ b2,
    const float* __restrict__ g2, const float* __restrict__ be2,
    const float* __restrict__ w3, const float* __restrict__ b3,
    const float* __restrict__ g3, const float* __restrict__ be3,
    const float* __restrict__ w4, const float* __restrict__ b4,
    const float* __restrict__ g4, const float* __restrict__ be4,
    const float* __restrict__ w5, const float* __restrict__ b5,
    const float* __restrict__ g5, const float* __restrict__ be5,
    const float* __restrict__ fc1w, const float* __restrict__ fc1b,
    const float* __restrict__ fc2w, const float* __restrict__ fc2b,
    float* __restrict__ h1, float* __restrict__ h2,
    float* __restrict__ h3, float* __restrict__ h4,
    float* __restrict__ stats2, float* __restrict__ stats3,
    float* __restrict__ stats4, float* __restrict__ stats5,
    float* __restrict__ spat5,
    float* __restrict__ coeff_out, float* __restrict__ splines_out,
    unsigned* __restrict__ bar)
{
    __shared__ float scs[64], shs[64];
    __shared__ float red[2][2][4];
    __shared__ float part[4][64][2];
    __shared__ float fsc5[128], fsh5[128];
    __shared__ float fch[1024], fh1[1024];
    __shared__ float fysn[240];
    __shared__ float fcoef[24][36];

    const int blk = blockIdx.x;
    const int t = threadIdx.x;

    // conv1: 3->8, 256->127   items = 8b * 4cg * 64tiles = 2048
    conv_phase<3, 8, 256, 127, 64, 8, false, false, true>(
        sm, w1, b1, nullptr, nullptr, nullptr, 0.f,
        h1, nullptr, scs, shs, red, blk, t);
    gridbar(bar + 0);

    // conv2: 8->16, 127->63   items = 8 * 8 * 16 = 1024
    conv_phase<8, 16, 127, 63, 16, 4, false, true, true>(
        h1, w2, b2, nullptr, nullptr, nullptr, 0.f,
        h2, stats2, scs, shs, red, blk, t);
    gridbar(bar + 1);

    // conv3: 16->32, 63->31 (BN2 on input)   items = 8 * 16 * 4 = 512
    conv_phase<16, 32, 63, 31, 4, 2, true, true, true>(
        h2, w3, b3, g2, be2, stats2, 1.0f / 31752.0f,
        h3, stats3, scs, shs, red, blk, t);
    gridbar(bar + 2);

    // conv4: 32->64, 31->15 (BN3 on input)   items = 8 * 32 * 1 = 256
    conv_phase<32, 64, 31, 15, 1, 1, true, true, true>(
        h3, w4, b4, g3, be3, stats3, 1.0f / 7688.0f,
        h4, stats4, scs, shs, red, blk, t);
    gridbar(bar + 3);

    // conv5: 64->128, 15->7 (BN4 on input), ci-split 4, stats+spat only.
    {
        if (t < 64) {
            float m = stats4[t] * (1.f / 1800.f);
            float v = stats4[64 + t] * (1.f / 1800.f) - m * m;
            float sc = g4[t] * rsqrtf(v + 1e-5f);
            scs[t] = sc;
            shs[t] = be4[t] - m * sc;
        }
        __syncthreads();
        const int cs = t >> 6, pp = t & 63;
        for (int it = 0; it < 2; ++it) {
            const int item = it * NBLK + blk;       // 512 = 8b * 64cg
            const int co0 = (item & 63) * 2;
            const int b   = item >> 6;
            const bool valid = pp < 49;
            float a0 = 0.f, a1 = 0.f;
            if (valid) {
                const int oh = pp / 7, ow = pp - oh * 7;
                const float* ib = h4 + (size_t)(b * 64 + cs * 16) * 225
                                     + (size_t)(2 * oh) * 15 + 2 * ow;
                const float* wp = w5 + (size_t)co0 * 576 + (size_t)cs * 144;
                for (int ci = 0; ci < 16; ci++) {
                    const float* ip = ib + ci * 225;
                    const float sc = scs[cs * 16 + ci], sh = shs[cs * 16 + ci];
                    #pragma unroll
                    for (int kh = 0; kh < 3; kh++) {
                        #pragma unroll
                        for (int kw = 0; kw < 3; kw++) {
                            const float xv = fmaf(ip[kh * 15 + kw], sc, sh);
                            a0 = fmaf(xv, wp[ci * 9 + kh * 3 + kw], a0);
                            a1 = fmaf(xv, wp[576 + ci * 9 + kh * 3 + kw], a1);
                        }
                    }
                }
            }
            part[cs][pp][0] = a0; part[cs][pp][1] = a1;
            __syncthreads();
            if (cs == 0) {
                float s0 = part[0][pp][0] + part[1][pp][0] + part[2][pp][0] + part[3][pp][0];
                float s1 = part[0][pp][1] + part[1][pp][1] + part[2][pp][1] + part[3][pp][1];
                float v0 = valid ? fmaxf(s0 + b5[co0], 0.f) : 0.f;
                float v1 = valid ? fmaxf(s1 + b5[co0 + 1], 0.f) : 0.f;
                float rs0 = v0, rq0 = v0 * v0, rs1 = v1, rq1 = v1 * v1;
                #pragma unroll
                for (int off = 32; off > 0; off >>= 1) {
                    rs0 += __shfl_down(rs0, off); rq0 += __shfl_down(rq0, off);
                    rs1 += __shfl_down(rs1, off); rq1 += __shfl_down(rq1, off);
                }
                if (pp == 0) {
                    atomicAdd(&stats5[co0], rs0);
                    atomicAdd(&stats5[128 + co0], rq0);
                    atomicAdd(&stats5[co0 + 1], rs1);
                    atomicAdd(&stats5[128 + co0 + 1], rq1);
                    spat5[b * 128 + co0] = rs0;
                    spat5[b * 128 + co0 + 1] = rs1;
                }
            }
            __syncthreads();
        }
    }
    gridbar(bar + 4);

    if (blk != 0) return;

    // ---- fc1 / fc2 / spline tail (block 0 only) ----
    if (t < 128) {
        float m = stats5[t] * (1.f / 392.f);
        float v = stats5[128 + t] * (1.f / 392.f) - m * m;
        float sc = g5[t] * rsqrtf(v + 1e-5f);
        fsc5[t] = sc;
        fsh5[t] = be5[t] - m * sc;
    }
    __syncthreads();

    for (int i = t; i < 1024; i += 256) {
        int c = i & 127;
        fch[i] = fmaf(fsc5[c], spat5[i] * (1.f / 49.f), fsh5[c]);
    }
    __syncthreads();

    for (int i = t; i < 1024; i += 256) {
        int b = i >> 7, j = i & 127;
        float acc = fc1b[j];
        for (int c = 0; c < 128; c++)
            acc = fmaf(fch[(b << 7) + c], fc1w[(j << 7) + c], acc);
        fh1[i] = fmaxf(acc, 0.f);
    }
    __syncthreads();

    if (t < 240) {
        int b = t / 30, k = t % 30;
        float acc = fc2b[k];
        for (int j = 0; j < 128; j++)
            acc = fmaf(fh1[(b << 7) + j], fc2w[(k << 7) + j], acc);
        fysn[t] = acc + (float)(k % 10) * STEP_F;   // + identity ramp
    }
    __syncthreads();

    if (t < 24) {
        float y[10];
        #pragma unroll
        for (int i = 0; i < 10; i++) y[i] = fysn[t * 10 + i];
        // Thomas solve: M[i-1] + 4 M[i] + M[i+1] = 486*(y[i-1]-2y[i]+y[i+1])
        float rhs[9], cp[9], dp[9];
        #pragma unroll
        for (int i = 1; i <= 8; i++)
            rhs[i] = 486.f * (y[i - 1] - 2.f * y[i] + y[i + 1]);
        cp[1] = 0.25f; dp[1] = rhs[1] * 0.25f;
        #pragma unroll
        for (int i = 2; i <= 8; i++) {
            float m = 1.f / (4.f - cp[i - 1]);
            cp[i] = m;
            dp[i] = (rhs[i] - dp[i - 1]) * m;
        }
        float M[10];
        M[0] = 0.f; M[9] = 0.f;
        M[8] = dp[8];
        #pragma unroll
        for (int i = 7; i >= 1; i--) M[i] = dp[i] - cp[i] * M[i + 1];
        #pragma unroll
        for (int i = 0; i < 9; i++) {
            float a = (M[i + 1] - M[i]) * 1.5f;               // /(6h), h=1/9
            float bb = M[i] * 0.5f;
            float cc = (y[i + 1] - y[i]) * 9.f - (M[i + 1] + 2.f * M[i]) * (STEP_F / 6.f);
            float dd = y[i];
            fcoef[t][i] = a; fcoef[t][9 + i] = bb; fcoef[t][18 + i] = cc; fcoef[t][27 + i] = dd;
            coeff_out[t * 36 + i] = a;
            coeff_out[t * 36 + 9 + i] = bb;
            coeff_out[t * 36 + 18 + i] = cc;
            coeff_out[t * 36 + 27 + i] = dd;
        }
    }
    __syncthreads();

    for (int i = t; i < 24 * 255; i += 256) {
        int bc = i / 255, k = i - bc * 255;
        float xv = (float)k * (1.0f / 255.0f);
        float xi = floorf(xv * 9.0f);
        xi = fminf(fmaxf(xi, 0.f), 8.f);
        int ix = (int)xi;
        float xf = xv - xi * STEP_F;
        const float* cf = fcoef[bc];
        splines_out[i] = fmaf(fmaf(fmaf(cf[ix], xf, cf[9 + ix]), xf, cf[18 + ix]), xf, cf[27 + ix]);
    }
}

// ---------------------------------------------------------------------------
// Apply spline to full-res x. One block = 1024 consecutive floats.
// ---------------------------------------------------------------------------
__global__ __launch_bounds__(256) void apply_k(const float* __restrict__ x,
                                               const float* __restrict__ coeff,
                                               float* __restrict__ out)
{
    __shared__ float cf[36];
    const int blk = blockIdx.x;
    const int plane = blk >> 10;           // 1024 blocks per 1M-float plane
    const int t = threadIdx.x;
    if (t < 36) cf[t] = coeff[plane * 36 + t];
    __syncthreads();

    size_t base = (size_t)blk * 1024 + (size_t)t * 4;
    float4 v = *(const float4*)(x + base);
    float4 o;
    #pragma unroll
    for (int k = 0; k < 4; k++) {
        float xv = (k == 0) ? v.x : (k == 1) ? v.y : (k == 2) ? v.z : v.w;
        float xi = floorf(xv * 9.0f);
        xi = fminf(fmaxf(xi, 0.f), 8.f);
        int ix = (int)xi;
        float xf = xv - xi * STEP_F;
        float r = fmaf(fmaf(fmaf(cf[ix], xf, cf[9 + ix]), xf, cf[18 + ix]), xf, cf[27 + ix]);
        if (k == 0) o.x = r; else if (k == 1) o.y = r; else if (k == 2) o.z = r; else o.w = r;
    }
    *(float4*)(out + base) = o;
}

// ---------------------------------------------------------------------------
extern "C" void kernel_launch(void* const* d_in, const int* in_sizes, int n_in,
                              void* d_out, int out_size, void* d_ws, size_t ws_size,
                              hipStream_t stream) {
    (void)in_sizes; (void)n_in; (void)out_size; (void)ws_size;

    const float* x    = (const float*)d_in[0];
    const float* w1   = (const float*)d_in[1];
    const float* b1   = (const float*)d_in[2];
    const float* w2   = (const float*)d_in[3];
    const float* b2   = (const float*)d_in[4];
    const float* g2   = (const float*)d_in[5];
    const float* be2  = (const float*)d_in[6];
    const float* w3   = (const float*)d_in[7];
    const float* b3   = (const float*)d_in[8];
    const float* g3   = (const float*)d_in[9];
    const float* be3  = (const float*)d_in[10];
    const float* w4   = (const float*)d_in[11];
    const float* b4   = (const float*)d_in[12];
    const float* g4   = (const float*)d_in[13];
    const float* be4  = (const float*)d_in[14];
    const float* w5   = (const float*)d_in[15];
    const float* b5   = (const float*)d_in[16];
    const float* g5   = (const float*)d_in[17];
    const float* be5  = (const float*)d_in[18];
    const float* fc1w = (const float*)d_in[19];
    const float* fc1b = (const float*)d_in[20];
    const float* fc2w = (const float*)d_in[21];
    const float* fc2b = (const float*)d_in[22];

    float* out = (float*)d_out;
    float* wsf = (float*)d_ws;

    // ws layout (floats); [0..2560) zeroed by resize_k block 0
    float* stats2 = wsf + 0;     // sum[16], sumsq[16]
    float* stats3 = wsf + 32;    // sum[32], sumsq[32]
    float* stats4 = wsf + 96;    // sum[64], sumsq[64]
    float* stats5 = wsf + 224;   // sum[128], sumsq[128]
    float* spat5  = wsf + 480;   // [8*128]
    float* coeff  = wsf + 1504;  // [24*36]
    unsigned* bar = (unsigned*)(wsf + 2400);  // 5 grid-barrier counters

    // big intermediates in d_out's first ~14 MB (overwritten by apply_k)
    float* sm  = out;                  // 24*256*256  = 1572864
    float* h1  = out + 1572864;        // 8*8*127*127 = 1032256
    float* h2  = out + 2605120;        // 8*16*63*63  =  508032
    float* h3  = out + 3113152;        // 8*32*31*31  =  246016
    float* h4  = out + 3359168;        // 8*64*15*15  =  115200

    resize_k<<<6144, 256, 0, stream>>>(x, sm, wsf);

    trunk_k<<<NBLK, 256, 0, stream>>>(
        sm,
        w1, b1, w2, b2, g2, be2, w3, b3, g3, be3,
        w4, b4, g4, be4, w5, b5, g5, be5,
        fc1w, fc1b, fc2w, fc2b,
        h1, h2, h3, h4,
        stats2, stats3, stats4, stats5, spat5,
        coeff, out + SPLINE_OFF, bar);

    apply_k<<<24576, 256, 0, stream>>>(x, coeff, out);
}

// Round 6
// 132.082 us; speedup vs baseline: 1.9395x; 1.9395x over previous
//
#include <hip/hip_runtime.h>

#define SPLINE_OFF 25165824   // splines output offset (6120 floats follow)
#define STEP_F (1.0f/9.0f)

typedef float f32x4 __attribute__((ext_vector_type(4)));

// ---------------------------------------------------------------------------
// Fused resize: jax.image.resize bilinear antialias, 1024 -> 256 (scale .25).
// Separable triangle kernel, 8 taps at stride 4, weights {1,3,5,7,7,5,3,1}/8,
// normalized by sum of valid taps. One block per (plane, output-row).
// ---------------------------------------------------------------------------
__global__ __launch_bounds__(256) void resize_k(const float* __restrict__ x,
                                                float* __restrict__ sm) {
    __shared__ float vsum[1024];
    const int blk = blockIdx.x;          // 24*256
    const int plane = blk >> 8;
    const int orow = blk & 255;
    const int t = threadIdx.x;

    const float W[8] = {0.125f,0.375f,0.625f,0.875f,0.875f,0.625f,0.375f,0.125f};
    const float* p = x + (size_t)plane * 1048576 + t * 4;
    const int r0 = 4 * orow - 2;
    float ax = 0.f, ay = 0.f, az = 0.f, aw = 0.f;
    if (r0 >= 0 && r0 + 7 <= 1023) {
        #pragma unroll
        for (int k = 0; k < 8; k++) {
            const float4 v = *(const float4*)(p + (r0 + k) * 1024);
            const float w = W[k] * 0.25f;
            ax = fmaf(v.x, w, ax); ay = fmaf(v.y, w, ay);
            az = fmaf(v.z, w, az); aw = fmaf(v.w, w, aw);
        }
    } else {
        float wsum = 0.f;
        #pragma unroll
        for (int k = 0; k < 8; k++) {
            const int r = r0 + k;
            if (r >= 0 && r < 1024) {
                const float4 v = *(const float4*)(p + r * 1024);
                ax = fmaf(v.x, W[k], ax); ay = fmaf(v.y, W[k], ay);
                az = fmaf(v.z, W[k], az); aw = fmaf(v.w, W[k], aw);
                wsum += W[k];
            }
        }
        const float inv = 1.f / wsum;
        ax *= inv; ay *= inv; az *= inv; aw *= inv;
    }
    vsum[4 * t + 0] = ax; vsum[4 * t + 1] = ay;
    vsum[4 * t + 2] = az; vsum[4 * t + 3] = aw;
    __syncthreads();

    const int c0 = 4 * t - 2;
    float acc = 0.f;
    if (c0 >= 0 && c0 + 7 <= 1023) {
        #pragma unroll
        for (int k = 0; k < 8; k++)
            acc = fmaf(vsum[c0 + k], W[k] * 0.25f, acc);
    } else {
        float wsum = 0.f;
        #pragma unroll
        for (int k = 0; k < 8; k++) {
            const int c = c0 + k;
            if (c >= 0 && c < 1024) { acc = fmaf(vsum[c], W[k], acc); wsum += W[k]; }
        }
        acc /= wsum;
    }
    sm[(size_t)blk * 256 + t] = acc;
}

// ---------------------------------------------------------------------------
// Direct 3x3 stride-2 VALID conv + bias + ReLU.  NO device atomics:
//  - INBN: previous layer's BN is derived by reducing that layer's per-block
//    partial sums (8*NTPREV slots per channel) in parallel, then folded into
//    the staged weights:  conv(sc*x+sh) = conv_{w*sc}(x) + C.
//  - STATS: this block's per-channel sum/sumsq (block-reduced) written to a
//    UNIQUE partial slot (b*COUT+co)*NTOUT + blockIdx.x  — plain stores.
//  - NCO=2 output channels per thread; CISPLIT-way input-channel split w/ LDS
//    reduction; WRITE=false skips storing the activation (conv5).
// Grid: (NTOUT, B * COUT/NCO). Block: PIX*CISPLIT threads.
// ---------------------------------------------------------------------------
template<int CIN, int COUT, int INW, int OUTW, int NCO, int CISPLIT, int PIX,
         int NTPREV, int NTOUT, bool INBN, bool STATS, bool WRITE>
__global__ __launch_bounds__(PIX * CISPLIT) void conv_k(
    const float* __restrict__ in, const float* __restrict__ w,
    const float* __restrict__ bias,
    const float* __restrict__ gam, const float* __restrict__ be,
    const float* __restrict__ pS, const float* __restrict__ pQ, float invN,
    float* __restrict__ out,
    float* __restrict__ pSo, float* __restrict__ pQo)
{
    constexpr int BLOCK = PIX * CISPLIT;
    constexpr int CPS = CIN / CISPLIT;
    constexpr int COG = COUT / NCO;

    __shared__ float wsm[NCO][CIN * 9];
    __shared__ float scs[CIN], shs[CIN];
    __shared__ float wrow[NCO][CIN];
    __shared__ float cadd[NCO];
    __shared__ float part[CISPLIT][PIX][NCO];
    __shared__ float red[NCO][2][PIX / 64];
    __shared__ float sredS[BLOCK], sredQ[BLOCK];

    const int tid = threadIdx.x;
    const int p   = tid & (PIX - 1);
    const int cs  = tid / PIX;
    const int bc  = blockIdx.y;
    const int b   = bc / COG;
    const int co0 = (bc % COG) * NCO;

    if constexpr (INBN) {
        // parallel reduce of previous layer's partials -> BN scale/shift
        constexpr int GRP = BLOCK / CIN;
        constexpr int TERMS = 8 * NTPREV;
        const int ci = tid % CIN;
        const int gi = tid / CIN;
        float s = 0.f, q = 0.f;
        for (int j = gi; j < TERMS; j += GRP) {
            const int bb = j / NTPREV, tl = j - bb * NTPREV;
            const int a = (bb * CIN + ci) * NTPREV + tl;
            s += pS[a]; q += pQ[a];
        }
        sredS[gi * CIN + ci] = s;
        sredQ[gi * CIN + ci] = q;
        __syncthreads();
        if (tid < CIN) {
            float ts = 0.f, tq = 0.f;
            #pragma unroll
            for (int g2 = 0; g2 < GRP; g2++) {
                ts += sredS[g2 * CIN + tid];
                tq += sredQ[g2 * CIN + tid];
            }
            const float m = ts * invN;
            const float v = tq * invN - m * m;
            const float sc = gam[tid] * rsqrtf(v + 1e-5f);
            scs[tid] = sc;
            shs[tid] = be[tid] - m * sc;
        }
        __syncthreads();
    }

    // stage weights (pre-scaled by BN sc) + raw row-sums for the constant
    for (int i = tid; i < NCO * CIN * 9; i += BLOCK) {
        int n = i / (CIN * 9), r = i - n * (CIN * 9), ci = r / 9;
        float wv = w[(co0 + n) * CIN * 9 + r];
        wsm[n][r] = INBN ? wv * scs[ci] : wv;
    }
    if constexpr (INBN) {
        for (int i = tid; i < NCO * CIN; i += BLOCK) {
            int n = i / CIN, ci = i - n * CIN;
            const float* wp = w + ((co0 + n) * CIN + ci) * 9;
            float s = 0.f;
            #pragma unroll
            for (int k = 0; k < 9; k++) s += wp[k];
            wrow[n][ci] = s;
        }
    }
    __syncthreads();
    if (tid < NCO) {
        float c = bias[co0 + tid];
        if constexpr (INBN) {
            for (int ci = 0; ci < CIN; ci++) c = fmaf(wrow[tid][ci], shs[ci], c);
        }
        cadd[tid] = c;
    }
    __syncthreads();

    const int npix = OUTW * OUTW;
    const int pg = blockIdx.x * PIX + p;
    float acc[NCO];
    #pragma unroll
    for (int n = 0; n < NCO; n++) acc[n] = 0.f;

    if (pg < npix) {
        const int oh = pg / OUTW, ow = pg - oh * OUTW;
        const float* ib = in + ((size_t)(b * CIN) + cs * CPS) * INW * INW
                             + (size_t)(2 * oh) * INW + 2 * ow;
        #pragma unroll 4
        for (int ci = 0; ci < CPS; ci++) {
            const float* ip = ib + (size_t)ci * INW * INW;
            const int cw = (cs * CPS + ci) * 9;
            #pragma unroll
            for (int kh = 0; kh < 3; kh++) {
                const float* r = ip + kh * INW;
                #pragma unroll
                for (int kw = 0; kw < 3; kw++) {
                    const float xv = r[kw];
                    #pragma unroll
                    for (int n = 0; n < NCO; n++)
                        acc[n] = fmaf(xv, wsm[n][cw + kh * 3 + kw], acc[n]);
                }
            }
        }
    }

    float val[NCO];
    #pragma unroll
    for (int n = 0; n < NCO; n++) val[n] = 0.f;

    if constexpr (CISPLIT > 1) {
        #pragma unroll
        for (int n = 0; n < NCO; n++) part[cs][p][n] = acc[n];
        __syncthreads();
    }

    if (cs == 0) {
        #pragma unroll
        for (int n = 0; n < NCO; n++) {
            float s = acc[n];
            if constexpr (CISPLIT > 1) {
                #pragma unroll
                for (int q = 1; q < CISPLIT; q++) s += part[q][p][n];
            }
            if (pg < npix) {
                val[n] = fmaxf(s + cadd[n], 0.f);
                if constexpr (WRITE)
                    out[(size_t)(b * COUT + co0 + n) * npix + pg] = val[n];
            }
        }
    }

    if constexpr (STATS) {
        if (cs == 0) {
            #pragma unroll
            for (int n = 0; n < NCO; n++) {
                float s = val[n], sq = val[n] * val[n];
                #pragma unroll
                for (int off = 32; off > 0; off >>= 1) {
                    s  += __shfl_down(s, off);
                    sq += __shfl_down(sq, off);
                }
                if ((tid & 63) == 0) { red[n][0][tid >> 6] = s; red[n][1][tid >> 6] = sq; }
            }
        }
        __syncthreads();
        if (tid == 0) {
            #pragma unroll
            for (int n = 0; n < NCO; n++) {
                float ts = 0.f, tq = 0.f;
                #pragma unroll
                for (int i = 0; i < PIX / 64; i++) { ts += red[n][0][i]; tq += red[n][1][i]; }
                const int idx = (b * COUT + co0 + n) * NTOUT + blockIdx.x;
                pSo[idx] = ts;
                pQo[idx] = tq;
            }
        }
    }
}

// ---------------------------------------------------------------------------
// Single-block: BN5 (from conv5 partials) -> spatial mean -> fc1(ReLU) -> fc2
// -> +identity -> natural cubic spline (Thomas solve) -> coeffs + splines.
// ---------------------------------------------------------------------------
__global__ __launch_bounds__(256) void fc_spline_k(
    const float* __restrict__ pS5, const float* __restrict__ pQ5,
    const float* __restrict__ g5, const float* __restrict__ be5,
    const float* __restrict__ fc1w, const float* __restrict__ fc1b,
    const float* __restrict__ fc2w, const float* __restrict__ fc2b,
    float* __restrict__ coeff_out, float* __restrict__ splines_out)
{
    __shared__ float sc5[128], sh5[128];
    __shared__ float h[1024];     // [b][c] b<8, c<128
    __shared__ float h1v[1024];
    __shared__ float ysn[240];    // [bc][10], bc = b*3+cch
    __shared__ float coef[24][36];

    const int t = threadIdx.x;

    if (t < 128) {
        float s = 0.f, q = 0.f;
        #pragma unroll
        for (int b = 0; b < 8; b++) { s += pS5[b * 128 + t]; q += pQ5[b * 128 + t]; }
        float m = s * (1.f / 392.f);
        float v = q * (1.f / 392.f) - m * m;
        float sc = g5[t] * rsqrtf(v + 1e-5f);
        sc5[t] = sc;
        sh5[t] = be5[t] - m * sc;
    }
    __syncthreads();

    for (int i = t; i < 1024; i += 256) {
        int c = i & 127;
        h[i] = fmaf(sc5[c], pS5[i] * (1.f / 49.f), sh5[c]);
    }
    __syncthreads();

    for (int i = t; i < 1024; i += 256) {
        int b = i >> 7, j = i & 127;
        float acc = fc1b[j];
        for (int c = 0; c < 128; c++)
            acc = fmaf(h[(b << 7) + c], fc1w[(j << 7) + c], acc);
        h1v[i] = fmaxf(acc, 0.f);
    }
    __syncthreads();

    if (t < 240) {
        int b = t / 30, k = t % 30;
        float acc = fc2b[k];
        for (int j = 0; j < 128; j++)
            acc = fmaf(h1v[(b << 7) + j], fc2w[(k << 7) + j], acc);
        ysn[t] = acc + (float)(k % 10) * STEP_F;   // + identity ramp
    }
    __syncthreads();

    if (t < 24) {
        float y[10];
        #pragma unroll
        for (int i = 0; i < 10; i++) y[i] = ysn[t * 10 + i];
        // Thomas solve: M[i-1] + 4 M[i] + M[i+1] = 486*(y[i-1]-2y[i]+y[i+1])
        float rhs[9], cp[9], dp[9];
        #pragma unroll
        for (int i = 1; i <= 8; i++)
            rhs[i] = 486.f * (y[i - 1] - 2.f * y[i] + y[i + 1]);
        cp[1] = 0.25f; dp[1] = rhs[1] * 0.25f;
        #pragma unroll
        for (int i = 2; i <= 8; i++) {
            float m = 1.f / (4.f - cp[i - 1]);
            cp[i] = m;
            dp[i] = (rhs[i] - dp[i - 1]) * m;
        }
        float M[10];
        M[0] = 0.f; M[9] = 0.f;
        M[8] = dp[8];
        #pragma unroll
        for (int i = 7; i >= 1; i--) M[i] = dp[i] - cp[i] * M[i + 1];
        #pragma unroll
        for (int i = 0; i < 9; i++) {
            float a = (M[i + 1] - M[i]) * 1.5f;               // /(6h), h=1/9
            float bb = M[i] * 0.5f;
            float cc = (y[i + 1] - y[i]) * 9.f - (M[i + 1] + 2.f * M[i]) * (STEP_F / 6.f);
            float dd = y[i];
            coef[t][i] = a; coef[t][9 + i] = bb; coef[t][18 + i] = cc; coef[t][27 + i] = dd;
            coeff_out[t * 36 + i] = a;
            coeff_out[t * 36 + 9 + i] = bb;
            coeff_out[t * 36 + 18 + i] = cc;
            coeff_out[t * 36 + 27 + i] = dd;
        }
    }
    __syncthreads();

    for (int i = t; i < 24 * 255; i += 256) {
        int bc = i / 255, k = i - bc * 255;
        float xv = (float)k * (1.0f / 255.0f);
        float xi = floorf(xv * 9.0f);
        xi = fminf(fmaxf(xi, 0.f), 8.f);
        int ix = (int)xi;
        float xf = xv - xi * STEP_F;
        const float* cf = coef[bc];
        splines_out[i] = fmaf(fmaf(fmaf(cf[ix], xf, cf[9 + ix]), xf, cf[18 + ix]), xf, cf[27 + ix]);
    }
}

// ---------------------------------------------------------------------------
// Apply spline to full-res x. One block = 1024 consecutive floats.
// Nontemporal stores: out is never re-read, keep x resident in L2/L3.
// ---------------------------------------------------------------------------
__global__ __launch_bounds__(256) void apply_k(const float* __restrict__ x,
                                               const float* __restrict__ coeff,
                                               float* __restrict__ out)
{
    __shared__ float cf[36];
    const int blk = blockIdx.x;
    const int plane = blk >> 10;           // 1024 blocks per 1M-float plane
    const int t = threadIdx.x;
    if (t < 36) cf[t] = coeff[plane * 36 + t];
    __syncthreads();

    size_t base = (size_t)blk * 1024 + (size_t)t * 4;
    float4 v = *(const float4*)(x + base);
    f32x4 o;
    #pragma unroll
    for (int k = 0; k < 4; k++) {
        float xv = (k == 0) ? v.x : (k == 1) ? v.y : (k == 2) ? v.z : v.w;
        float xi = floorf(xv * 9.0f);
        xi = fminf(fmaxf(xi, 0.f), 8.f);
        int ix = (int)xi;
        float xf = xv - xi * STEP_F;
        o[k] = fmaf(fmaf(fmaf(cf[ix], xf, cf[9 + ix]), xf, cf[18 + ix]), xf, cf[27 + ix]);
    }
    __builtin_nontemporal_store(o, (f32x4*)(out + base));
}

// ---------------------------------------------------------------------------
extern "C" void kernel_launch(void* const* d_in, const int* in_sizes, int n_in,
                              void* d_out, int out_size, void* d_ws, size_t ws_size,
                              hipStream_t stream) {
    (void)in_sizes; (void)n_in; (void)out_size; (void)ws_size;

    const float* x    = (const float*)d_in[0];
    const float* w1   = (const float*)d_in[1];
    const float* b1   = (const float*)d_in[2];
    const float* w2   = (const float*)d_in[3];
    const float* b2   = (const float*)d_in[4];
    const float* g2   = (const float*)d_in[5];
    const float* be2  = (const float*)d_in[6];
    const float* w3   = (const float*)d_in[7];
    const float* b3   = (const float*)d_in[8];
    const float* g3   = (const float*)d_in[9];
    const float* be3  = (const float*)d_in[10];
    const float* w4   = (const float*)d_in[11];
    const float* b4   = (const float*)d_in[12];
    const float* g4   = (const float*)d_in[13];
    const float* be4  = (const float*)d_in[14];
    const float* w5   = (const float*)d_in[15];
    const float* b5   = (const float*)d_in[16];
    const float* g5   = (const float*)d_in[17];
    const float* be5  = (const float*)d_in[18];
    const float* fc1w = (const float*)d_in[19];
    const float* fc1b = (const float*)d_in[20];
    const float* fc2w = (const float*)d_in[21];
    const float* fc2b = (const float*)d_in[22];

    float* out = (float*)d_out;
    float* wsf = (float*)d_ws;

    // ws: per-block partial sums (no atomics; fully overwritten every call)
    float* pS2 = wsf + 0;      // [8*16*16]  = 2048
    float* pQ2 = wsf + 2048;   //            = 2048
    float* pS3 = wsf + 4096;   // [8*32*4]   = 1024
    float* pQ3 = wsf + 5120;   //            = 1024
    float* pS4 = wsf + 6144;   // [8*64*1]   =  512
    float* pQ4 = wsf + 6656;   //            =  512
    float* pS5 = wsf + 7168;   // [8*128]    = 1024  (= spat5)
    float* pQ5 = wsf + 8192;   //            = 1024
    float* coeff = wsf + 9216; // [24*36]

    // big intermediates in d_out's first ~14 MB (overwritten by apply_k)
    float* sm  = out;                  // 24*256*256  = 1572864
    float* h1  = out + 1572864;        // 8*8*127*127 = 1032256
    float* h2  = out + 2605120;        // 8*16*63*63  =  508032
    float* h3  = out + 3113152;        // 8*32*31*31  =  246016
    float* h4  = out + 3359168;        // 8*64*15*15  =  115200

    resize_k<<<6144, 256, 0, stream>>>(x, sm);

    // conv1: 3->8, 256->127
    conv_k<3, 8, 256, 127, 2, 1, 256, 1, 1, false, false, true>
        <<<dim3(64, 32), 256, 0, stream>>>(sm, w1, b1, nullptr, nullptr,
                                           nullptr, nullptr, 0.f,
                                           h1, nullptr, nullptr);
    // conv2: 8->16, 127->63  (writes 16-tile partials)
    conv_k<8, 16, 127, 63, 2, 1, 256, 1, 16, false, true, true>
        <<<dim3(16, 64), 256, 0, stream>>>(h1, w2, b2, nullptr, nullptr,
                                           nullptr, nullptr, 0.f,
                                           h2, pS2, pQ2);
    // conv3: 16->32, 63->31  (BN2 from pS2/pQ2; writes 4-tile partials)
    conv_k<16, 32, 63, 31, 2, 1, 256, 16, 4, true, true, true>
        <<<dim3(4, 128), 256, 0, stream>>>(h2, w3, b3, g2, be2,
                                           pS2, pQ2, 1.0f / 31752.0f,
                                           h3, pS3, pQ3);
    // conv4: 32->64, 31->15  (BN3; ci-split 2; 1-tile partials)
    conv_k<32, 64, 31, 15, 2, 2, 256, 4, 1, true, true, true>
        <<<dim3(1, 256), 512, 0, stream>>>(h3, w4, b4, g3, be3,
                                           pS3, pQ3, 1.0f / 7688.0f,
                                           h4, pS4, pQ4);
    // conv5: 64->128, 15->7  (BN4; ci-split 4; stats only, no store)
    conv_k<64, 128, 15, 7, 2, 4, 64, 1, 1, true, true, false>
        <<<dim3(1, 512), 256, 0, stream>>>(h4, w5, b5, g4, be4,
                                           pS4, pQ4, 1.0f / 1800.0f,
                                           nullptr, pS5, pQ5);

    fc_spline_k<<<1, 256, 0, stream>>>(pS5, pQ5, g5, be5,
                                       fc1w, fc1b, fc2w, fc2b,
                                       coeff, out + SPLINE_OFF);

    apply_k<<<24576, 256, 0, stream>>>(x, coeff, out);
}